// Round 6
// baseline (209.746 us; speedup 1.0000x reference)
//
#include <hip/hip_runtime.h>
#include <hip/hip_bf16.h>

typedef __bf16 bf16x8 __attribute__((ext_vector_type(8)));
typedef float f32x4 __attribute__((ext_vector_type(4)));
typedef float f32x16 __attribute__((ext_vector_type(16)));
typedef unsigned short ushort_t;
typedef unsigned short ushort8 __attribute__((ext_vector_type(8)));
typedef unsigned int uint4v __attribute__((ext_vector_type(4)));

// ---------- helpers ----------

__device__ inline void gload_lds16(const void* g, void* l) {
  __builtin_amdgcn_global_load_lds(
      (const __attribute__((address_space(1))) void*)g,
      (__attribute__((address_space(3))) void*)l, 16, 0, 0);
}

// fp32 -> bf16 round-to-nearest-even (bit manipulation)
__device__ inline ushort_t f2bf(float f) {
  unsigned int u = __float_as_uint(f);
  unsigned int lsb = (u >> 16) & 1u;
  u += 0x7fffu + lsb;
  return (ushort_t)(u >> 16);
}

// ---------- conversion kernels ----------

__global__ __launch_bounds__(256) void f32_to_bf16_vec(
    const float* __restrict__ in, ushort_t* __restrict__ out) {
  int i = (blockIdx.x * 256 + threadIdx.x) * 8;
  float4 a = *(const float4*)&in[i];
  float4 b = *(const float4*)&in[i + 4];
  ushort8 o;
  o[0] = f2bf(a.x); o[1] = f2bf(a.y); o[2] = f2bf(a.z); o[3] = f2bf(a.w);
  o[4] = f2bf(b.x); o[5] = f2bf(b.y); o[6] = f2bf(b.z); o[7] = f2bf(b.w);
  *(ushort8*)&out[i] = o;
}

// in [R][C] fp32 -> out [C][R] bf16 (LDS-tiled)
__global__ __launch_bounds__(256) void transpose_f32_bf16(
    const float* __restrict__ in, ushort_t* __restrict__ out, int R, int C) {
  __shared__ float tile[32][33];
  const int tx = threadIdx.x & 31, ty = threadIdx.x >> 5;  // 32 x 8
  const int c0 = blockIdx.x * 32, r0 = blockIdx.y * 32;
#pragma unroll
  for (int i = 0; i < 32; i += 8)
    tile[ty + i][tx] = in[(size_t)(r0 + ty + i) * C + c0 + tx];
  __syncthreads();
#pragma unroll
  for (int i = 0; i < 32; i += 8)
    out[(size_t)(c0 + ty + i) * R + r0 + tx] = f2bf(tile[tx][ty + i]);
}

// V-part of kqv [4096][3072] -> vt[bh][64 dh][2048 t]  (bf16 transpose)
__global__ __launch_bounds__(256) void transpose_v(
    const ushort_t* __restrict__ kqv, ushort_t* __restrict__ vt) {
  __shared__ ushort_t tile[64 * 64];  // 16B-slot XOR swizzle
  const int tt = blockIdx.x;  // t tile (0..31)
  const int bh = blockIdx.y;  // 0..31
  const int b = bh >> 4, h = bh & 15;
  const int tid = threadIdx.x;
#pragma unroll
  for (int p = 0; p < 2; p++) {
    const int tr = (tid >> 3) + p * 32;
    const int c8 = tid & 7;
    ushort8 v = *(const ushort8*)&kqv[(size_t)(b * 2048 + tt * 64 + tr) * 3072 +
                                      2048 + h * 64 + c8 * 8];
    *(ushort8*)&tile[tr * 64 + ((c8 ^ (tr & 7)) * 8)] = v;
  }
  __syncthreads();
  const int d = tid & 63;
#pragma unroll
  for (int p = 0; p < 2; p++) {
    const int t8 = (tid >> 6) + p * 4;  // 8-t chunk 0..7
    ushort8 o;
#pragma unroll
    for (int j = 0; j < 8; j++) {
      const int t = t8 * 8 + j;
      o[j] = tile[t * 64 + (((d >> 3) ^ (t & 7)) * 8) + (d & 7)];
    }
    *(ushort8*)&vt[(size_t)(bh * 64 + d) * 2048 + tt * 64 + t8 * 8] = o;
  }
}

// ---------- GEMM: C = A @ B (+bias), A[M][K] bf16, BT[N][K] bf16 ----------
// (unchanged — known-good m97 structure; control)

template <bool OUT_BF16>
__global__ __launch_bounds__(256) void gemm_bt(
    const ushort_t* __restrict__ A, const ushort_t* __restrict__ BT,
    const float* __restrict__ bias, void* __restrict__ Cout,
    int M, int N, int K) {
  __shared__ ushort_t lA[128 * 32];
  __shared__ ushort_t lB[128 * 32];
  const int tid = threadIdx.x;
  const int lane = tid & 63;
  const int wave = tid >> 6;
  const int wr = wave >> 1, wc = wave & 1;
  const int l16 = lane & 15, lhi = lane >> 4;
  const int bx = blockIdx.x, by = blockIdx.y;

  const ushort_t* gA = A + (size_t)(by * 128 + (tid >> 2)) * K + (tid & 3) * 8;
  const ushort_t* gB = BT + (size_t)(bx * 128 + (tid >> 2)) * K + (tid & 3) * 8;

  f32x4 acc[4][4] = {};

  for (int k0 = 0; k0 < K; k0 += 32) {
    gload_lds16(gA + k0, &lA[tid * 8]);
    gload_lds16(gA + k0 + (size_t)64 * K, &lA[tid * 8 + 2048]);
    gload_lds16(gB + k0, &lB[tid * 8]);
    gload_lds16(gB + k0 + (size_t)64 * K, &lB[tid * 8 + 2048]);
    __syncthreads();

    bf16x8 af[4], bfr[4];
#pragma unroll
    for (int m = 0; m < 4; m++)
      af[m] = *(const bf16x8*)&lA[(wr * 64 + m * 16 + l16) * 32 + lhi * 8];
#pragma unroll
    for (int n = 0; n < 4; n++)
      bfr[n] = *(const bf16x8*)&lB[(wc * 64 + n * 16 + l16) * 32 + lhi * 8];
#pragma unroll
    for (int m = 0; m < 4; m++)
#pragma unroll
      for (int n = 0; n < 4; n++)
        acc[m][n] = __builtin_amdgcn_mfma_f32_16x16x32_bf16(af[m], bfr[n],
                                                            acc[m][n], 0, 0, 0);
    __syncthreads();
  }

  const int r0 = by * 128 + wr * 64 + lhi * 4;
  const int c0 = bx * 128 + wc * 64 + l16;
#pragma unroll
  for (int m = 0; m < 4; m++)
#pragma unroll
    for (int n = 0; n < 4; n++) {
      const int col = c0 + n * 16;
      const float bv = bias[col];
#pragma unroll
      for (int j = 0; j < 4; j++) {
        const int row = r0 + m * 16 + j;
        const float v = acc[m][n][j] + bv;
        if (OUT_BF16)
          ((ushort_t*)Cout)[(size_t)row * N + col] = f2bf(v);
        else
          ((float*)Cout)[(size_t)row * N + col] = v;
      }
    }
}

// ---------- attention (softmax-free, causal) ----------
// 256 threads = 4 waves; block = (b,h) x 128 Q rows; wave = 32 q-rows.
// 32x32x16 MFMA, swapped QK^T (St = K·Q^T in regs), in-register P via
// v_cvt_pk_bf16_f32 + v_permlane32_swap (T12) -> PV directly. NO S LDS
// round-trip. K/V^T staged swizzled via global_load_lds; 3-buffer
// counted-vmcnt pipeline (T3/T4); XCD-bijective swizzle (T1).

__global__ __launch_bounds__(256) void attn_kernel(
    const ushort_t* __restrict__ kqv, const ushort_t* __restrict__ vt,
    ushort_t* __restrict__ ao) {
  __shared__ ushort_t lK[3][64 * 64];
  __shared__ ushort_t lVT[3][64 * 64];
  const int tid = threadIdx.x, lane = tid & 63, wave = tid >> 6;
  const int q_rel = lane & 31, hi = lane >> 5;
  // XCD swizzle: 512 blocks; xcd = L&7 gets 64 consecutive work ids = 4 bh.
  const int L = blockIdx.x;
  const int W = (L & 7) * 64 + (L >> 3);
  const int qi = 15 - (W & 15);  // heavy tiles first (LPT)
  const int bh = W >> 4;
  const int b = bh >> 4, h = bh & 15;
  const int q0 = qi * 128;
  const ushort_t* base = kqv + (size_t)b * 2048 * 3072;
  const ushort_t* vbase = vt + (size_t)bh * 64 * 2048;

  // staging: 512 slots of 16B; thread covers slot tid and tid+256.
  // slot -> row = slot>>3, chunk = slot&7; source pre-swizzled (XOR (row&7)).
  size_t kg[2], vg[2];
  int ld[2];
#pragma unroll
  for (int p = 0; p < 2; p++) {
    const int slot = tid + p * 256;
    const int srow = slot >> 3;
    const int scb = (((slot & 7) * 16) ^ ((srow & 7) << 4)) >> 1;  // elem offset
    kg[p] = (size_t)srow * 3072 + h * 64 + scb;
    vg[p] = (size_t)srow * 2048 + scb;
    ld[p] = slot * 8;
  }

  // Q fragments in registers: B-frag rows q = wq0 + q_rel, dh slices
  const int wq0 = q0 + wave * 32;
  bf16x8 qf[4];
#pragma unroll
  for (int ds = 0; ds < 4; ds++)
    qf[ds] = *(const bf16x8*)&base[(size_t)(wq0 + q_rel) * 3072 + 1024 + h * 64 +
                                   ds * 16 + hi * 8];

  f32x16 oacc[2] = {};
  const int nkt = qi * 2 + 2;  // causal K tiles (>= 2 always)

  // prologue: stage tiles 0 and 1
#pragma unroll
  for (int p = 0; p < 2; p++) {
    gload_lds16(&base[kg[p]], &lK[0][ld[p]]);
    gload_lds16(&vbase[vg[p]], &lVT[0][ld[p]]);
  }
#pragma unroll
  for (int p = 0; p < 2; p++) {
    gload_lds16(&base[(size_t)64 * 3072 + kg[p]], &lK[1][ld[p]]);
    gload_lds16(&vbase[64 + vg[p]], &lVT[1][ld[p]]);
  }

  int cur = 0;
  for (int kt = 0; kt < nkt; ++kt) {
    // own tile-kt loads done; tile kt+1's 4 loads may stay in flight
    if (kt + 1 < nkt) asm volatile("s_waitcnt vmcnt(4)" ::: "memory");
    else              asm volatile("s_waitcnt vmcnt(0)" ::: "memory");
    __builtin_amdgcn_s_barrier();
    asm volatile("" ::: "memory");

    // prefetch tile kt+2 into buffer last read at iteration kt-1
    if (kt + 2 < nkt) {
      const int pf = (cur + 2 >= 3) ? cur - 1 : cur + 2;
#pragma unroll
      for (int p = 0; p < 2; p++) {
        gload_lds16(&base[(size_t)(kt + 2) * 64 * 3072 + kg[p]], &lK[pf][ld[p]]);
        gload_lds16(&vbase[(size_t)(kt + 2) * 64 + vg[p]], &lVT[pf][ld[p]]);
      }
    }

    // wave-uniform skip: tile entirely above this wave's diagonal
    if (kt * 64 <= wq0 + 31) {
      const bool need_mask = (kt * 64 + 63) > wq0;
#pragma unroll
      for (int kb = 0; kb < 2; kb++) {
        // St = K·Q^T (32x32): lane holds St[k][q=q_rel], k=(r&3)+8*(r>>2)+4*hi
        f32x16 st = {};
        const int krow = kb * 32 + q_rel;
        const int ksw = krow & 7;
#pragma unroll
        for (int ds = 0; ds < 4; ds++) {
          bf16x8 kf = *(const bf16x8*)&lK[cur][krow * 64 + (((ds * 2 + hi) ^ ksw) * 8)];
          st = __builtin_amdgcn_mfma_f32_32x32x16_bf16(kf, qf[ds], st, 0, 0, 0);
        }
        // causal mask (pre-conversion)
        if (need_mask) {
#pragma unroll
          for (int r = 0; r < 16; r++) {
            const int kgl = kt * 64 + kb * 32 + (r & 3) + 8 * (r >> 2) + 4 * hi;
            if (kgl > wq0 + q_rel) st[r] = 0.f;
          }
        }
        // T12: f32 -> packed bf16 + permlane32_swap -> PV A-frags
        unsigned int w0, w1, w2, w3, w4, w5, w6, w7;
        {
          float e0 = st[0], e1 = st[1], e2 = st[2], e3 = st[3];
          float e4 = st[4], e5 = st[5], e6 = st[6], e7 = st[7];
          float e8 = st[8], e9 = st[9], e10 = st[10], e11 = st[11];
          float e12 = st[12], e13 = st[13], e14 = st[14], e15 = st[15];
          asm("v_cvt_pk_bf16_f32 %0, %1, %2" : "=v"(w0) : "v"(e0), "v"(e1));
          asm("v_cvt_pk_bf16_f32 %0, %1, %2" : "=v"(w1) : "v"(e2), "v"(e3));
          asm("v_cvt_pk_bf16_f32 %0, %1, %2" : "=v"(w2) : "v"(e4), "v"(e5));
          asm("v_cvt_pk_bf16_f32 %0, %1, %2" : "=v"(w3) : "v"(e6), "v"(e7));
          asm("v_cvt_pk_bf16_f32 %0, %1, %2" : "=v"(w4) : "v"(e8), "v"(e9));
          asm("v_cvt_pk_bf16_f32 %0, %1, %2" : "=v"(w5) : "v"(e10), "v"(e11));
          asm("v_cvt_pk_bf16_f32 %0, %1, %2" : "=v"(w6) : "v"(e12), "v"(e13));
          asm("v_cvt_pk_bf16_f32 %0, %1, %2" : "=v"(w7) : "v"(e14), "v"(e15));
        }
        // exchange lane halves: after swap, words = (k0k1|k8k9) etc.
        asm("v_permlane32_swap_b32 %0, %1" : "+v"(w0), "+v"(w2));
        asm("v_permlane32_swap_b32 %0, %1" : "+v"(w1), "+v"(w3));
        asm("v_permlane32_swap_b32 %0, %1" : "+v"(w4), "+v"(w6));
        asm("v_permlane32_swap_b32 %0, %1" : "+v"(w5), "+v"(w7));
        uint4v u0 = {w0, w1, w2, w3};  // P[q=q_rel][k = kb*32 + hi*8 + 0..7]
        uint4v u1 = {w4, w5, w6, w7};  // P[q=q_rel][k = kb*32 + 16 + hi*8 + 0..7]
        bf16x8 pa0 = __builtin_bit_cast(bf16x8, u0);
        bf16x8 pa1 = __builtin_bit_cast(bf16x8, u1);
        // O += P·V : B-frag from lVT[d][k]
#pragma unroll
        for (int dt = 0; dt < 2; dt++) {
          const int vrow = dt * 32 + q_rel;
          const int vsw = vrow & 7;
          bf16x8 vf0 = *(const bf16x8*)&lVT[cur][vrow * 64 + (((kb * 4 + hi) ^ vsw) * 8)];
          bf16x8 vf1 = *(const bf16x8*)&lVT[cur][vrow * 64 + (((kb * 4 + 2 + hi) ^ vsw) * 8)];
          oacc[dt] = __builtin_amdgcn_mfma_f32_32x32x16_bf16(pa0, vf0, oacc[dt], 0, 0, 0);
          oacc[dt] = __builtin_amdgcn_mfma_f32_32x32x16_bf16(pa1, vf1, oacc[dt], 0, 0, 0);
        }
      }
    }

    cur = (cur + 1 >= 3) ? 0 : cur + 1;
  }

  // write O -> ao: col=lane&31 -> d, row q=(r&3)+8*(r>>2)+4*hi
#pragma unroll
  for (int dt = 0; dt < 2; dt++)
#pragma unroll
    for (int r = 0; r < 16; r++) {
      const int q = (r & 3) + 8 * (r >> 2) + 4 * hi;
      const int row = wq0 + q;
      const int col = h * 64 + dt * 32 + q_rel;
      ao[(size_t)(b * 2048 + row) * 1024 + col] = f2bf(oacc[dt][r]);
    }
}

// ---------- launch ----------

extern "C" void kernel_launch(void* const* d_in, const int* in_sizes, int n_in,
                              void* d_out, int out_size, void* d_ws, size_t ws_size,
                              hipStream_t stream) {
  const float* x  = (const float*)d_in[0];
  const float* W1 = (const float*)d_in[1];
  const float* b1 = (const float*)d_in[2];
  const float* W2 = (const float*)d_in[3];
  const float* b2 = (const float*)d_in[4];
  float* out = (float*)d_out;

  char* ws = (char*)d_ws;
  ushort_t* xb  = (ushort_t*)(ws);                 //  8 MB: x bf16 [4096][1024]
  ushort_t* w1t = (ushort_t*)(ws + 8388608);       //  6 MB: W1^T bf16 [3072][1024]
  ushort_t* w2t = (ushort_t*)(ws + 14680064);      //  2 MB: W2^T bf16 [1024][1024]
  ushort_t* kqv = (ushort_t*)(ws + 16777216);      // 24 MB: kqv bf16 [4096][3072]
  ushort_t* ao  = (ushort_t*)(ws + 41943040);      //  8 MB: attn out bf16 [4096][1024]
  ushort_t* vtb = (ushort_t*)(ws);                 //  8 MB: V^T (aliases xb; xb dead after gemm1)

  f32_to_bf16_vec<<<2048, 256, 0, stream>>>(x, xb);
  transpose_f32_bf16<<<dim3(96, 32), 256, 0, stream>>>(W1, w1t, 1024, 3072);
  transpose_f32_bf16<<<dim3(32, 32), 256, 0, stream>>>(W2, w2t, 1024, 1024);
  gemm_bt<true ><<<dim3(24, 32), 256, 0, stream>>>(xb, w1t, b1, kqv, 4096, 3072, 1024);
  transpose_v<<<dim3(32, 32), 256, 0, stream>>>(kqv, vtb);
  attn_kernel<<<dim3(512), 256, 0, stream>>>(kqv, vtb, ao);
  gemm_bt<false><<<dim3(8, 32), 256, 0, stream>>>(ao, w2t, b2, out, 4096, 1024, 1024);
}

// Round 7
// 199.155 us; speedup vs baseline: 1.0532x; 1.0532x over previous
//
#include <hip/hip_runtime.h>
#include <hip/hip_bf16.h>

typedef __bf16 bf16x8 __attribute__((ext_vector_type(8)));
typedef float f32x4 __attribute__((ext_vector_type(4)));
typedef float f32x16 __attribute__((ext_vector_type(16)));
typedef unsigned short ushort_t;
typedef unsigned short ushort8 __attribute__((ext_vector_type(8)));
typedef unsigned int uint4v __attribute__((ext_vector_type(4)));

// ---------- helpers ----------

__device__ inline void gload_lds16(const void* g, void* l) {
  __builtin_amdgcn_global_load_lds(
      (const __attribute__((address_space(1))) void*)g,
      (__attribute__((address_space(3))) void*)l, 16, 0, 0);
}

// fp32 -> bf16 round-to-nearest-even (bit manipulation)
__device__ inline ushort_t f2bf(float f) {
  unsigned int u = __float_as_uint(f);
  unsigned int lsb = (u >> 16) & 1u;
  u += 0x7fffu + lsb;
  return (ushort_t)(u >> 16);
}

// ---------- conversion kernels ----------

__global__ __launch_bounds__(256) void f32_to_bf16_vec(
    const float* __restrict__ in, ushort_t* __restrict__ out) {
  int i = (blockIdx.x * 256 + threadIdx.x) * 8;
  float4 a = *(const float4*)&in[i];
  float4 b = *(const float4*)&in[i + 4];
  ushort8 o;
  o[0] = f2bf(a.x); o[1] = f2bf(a.y); o[2] = f2bf(a.z); o[3] = f2bf(a.w);
  o[4] = f2bf(b.x); o[5] = f2bf(b.y); o[6] = f2bf(b.z); o[7] = f2bf(b.w);
  *(ushort8*)&out[i] = o;
}

// in [R][C] fp32 -> out [C][R] bf16 (LDS-tiled)
__global__ __launch_bounds__(256) void transpose_f32_bf16(
    const float* __restrict__ in, ushort_t* __restrict__ out, int R, int C) {
  __shared__ float tile[32][33];
  const int tx = threadIdx.x & 31, ty = threadIdx.x >> 5;  // 32 x 8
  const int c0 = blockIdx.x * 32, r0 = blockIdx.y * 32;
#pragma unroll
  for (int i = 0; i < 32; i += 8)
    tile[ty + i][tx] = in[(size_t)(r0 + ty + i) * C + c0 + tx];
  __syncthreads();
#pragma unroll
  for (int i = 0; i < 32; i += 8)
    out[(size_t)(c0 + ty + i) * R + r0 + tx] = f2bf(tile[tx][ty + i]);
}

// V-part of kqv [4096][3072] -> vt[bh][64 dh][2048 t]  (bf16 transpose)
__global__ __launch_bounds__(256) void transpose_v(
    const ushort_t* __restrict__ kqv, ushort_t* __restrict__ vt) {
  __shared__ ushort_t tile[64 * 64];  // 16B-slot XOR swizzle
  const int tt = blockIdx.x;  // t tile (0..31)
  const int bh = blockIdx.y;  // 0..31
  const int b = bh >> 4, h = bh & 15;
  const int tid = threadIdx.x;
#pragma unroll
  for (int p = 0; p < 2; p++) {
    const int tr = (tid >> 3) + p * 32;
    const int c8 = tid & 7;
    ushort8 v = *(const ushort8*)&kqv[(size_t)(b * 2048 + tt * 64 + tr) * 3072 +
                                      2048 + h * 64 + c8 * 8];
    *(ushort8*)&tile[tr * 64 + ((c8 ^ (tr & 7)) * 8)] = v;
  }
  __syncthreads();
  const int d = tid & 63;
#pragma unroll
  for (int p = 0; p < 2; p++) {
    const int t8 = (tid >> 6) + p * 4;  // 8-t chunk 0..7
    ushort8 o;
#pragma unroll
    for (int j = 0; j < 8; j++) {
      const int t = t8 * 8 + j;
      o[j] = tile[t * 64 + (((d >> 3) ^ (t & 7)) * 8) + (d & 7)];
    }
    *(ushort8*)&vt[(size_t)(bh * 64 + d) * 2048 + tt * 64 + t8 * 8] = o;
  }
}

// ---------- GEMM: C = A @ B (+bias), A[M][K] bf16, BT[N][K] bf16 ----------
// (unchanged — known-good m97 structure; control)

template <bool OUT_BF16>
__global__ __launch_bounds__(256) void gemm_bt(
    const ushort_t* __restrict__ A, const ushort_t* __restrict__ BT,
    const float* __restrict__ bias, void* __restrict__ Cout,
    int M, int N, int K) {
  __shared__ ushort_t lA[128 * 32];
  __shared__ ushort_t lB[128 * 32];
  const int tid = threadIdx.x;
  const int lane = tid & 63;
  const int wave = tid >> 6;
  const int wr = wave >> 1, wc = wave & 1;
  const int l16 = lane & 15, lhi = lane >> 4;
  const int bx = blockIdx.x, by = blockIdx.y;

  const ushort_t* gA = A + (size_t)(by * 128 + (tid >> 2)) * K + (tid & 3) * 8;
  const ushort_t* gB = BT + (size_t)(bx * 128 + (tid >> 2)) * K + (tid & 3) * 8;

  f32x4 acc[4][4] = {};

  for (int k0 = 0; k0 < K; k0 += 32) {
    gload_lds16(gA + k0, &lA[tid * 8]);
    gload_lds16(gA + k0 + (size_t)64 * K, &lA[tid * 8 + 2048]);
    gload_lds16(gB + k0, &lB[tid * 8]);
    gload_lds16(gB + k0 + (size_t)64 * K, &lB[tid * 8 + 2048]);
    __syncthreads();

    bf16x8 af[4], bfr[4];
#pragma unroll
    for (int m = 0; m < 4; m++)
      af[m] = *(const bf16x8*)&lA[(wr * 64 + m * 16 + l16) * 32 + lhi * 8];
#pragma unroll
    for (int n = 0; n < 4; n++)
      bfr[n] = *(const bf16x8*)&lB[(wc * 64 + n * 16 + l16) * 32 + lhi * 8];
#pragma unroll
    for (int m = 0; m < 4; m++)
#pragma unroll
      for (int n = 0; n < 4; n++)
        acc[m][n] = __builtin_amdgcn_mfma_f32_16x16x32_bf16(af[m], bfr[n],
                                                            acc[m][n], 0, 0, 0);
    __syncthreads();
  }

  const int r0 = by * 128 + wr * 64 + lhi * 4;
  const int c0 = bx * 128 + wc * 64 + l16;
#pragma unroll
  for (int m = 0; m < 4; m++)
#pragma unroll
    for (int n = 0; n < 4; n++) {
      const int col = c0 + n * 16;
      const float bv = bias[col];
#pragma unroll
      for (int j = 0; j < 4; j++) {
        const int row = r0 + m * 16 + j;
        const float v = acc[m][n][j] + bv;
        if (OUT_BF16)
          ((ushort_t*)Cout)[(size_t)row * N + col] = f2bf(v);
        else
          ((float*)Cout)[(size_t)row * N + col] = v;
      }
    }
}

// ---------- attention (softmax-free, causal) ----------
// 1024 blocks = (bh, qj 0..31): block = 64 q-rows, de-resonant qj stagger so
// any periodic block->CU assignment mixes heavy/light blocks (round-6 lesson:
// grid 512 resonated -> CU got 2 equal-weight blocks -> 1.9x makespan).
// 4 waves = (qs 2 x kb 2): q-half x kv-half, each wave its own partial O;
// epilogue LDS f32 reduce. 32x32x16 MFMA, swapped QK^T, in-register P via
// cvt_pk+permlane32 (layouts HW-verified in round 6). 2 LDS buffers (32KB),
// 1 barrier/tile: vmcnt(0) -> barrier -> prefetch kt+1 -> compute kt.

__global__ __launch_bounds__(256) void attn_kernel(
    const ushort_t* __restrict__ kqv, const ushort_t* __restrict__ vt,
    ushort_t* __restrict__ ao) {
  __shared__ ushort_t lK[2][64 * 64];   // 16 KB
  __shared__ ushort_t lVT[2][64 * 64];  // 16 KB
  const int tid = threadIdx.x, lane = tid & 63, wave = tid >> 6;
  const int q_rel = lane & 31, hi = lane >> 5;
  const int qs = wave & 1, kb = wave >> 1;
  // bijective XCD swizzle (4 bh per XCD) + per-bh qj stagger (de-resonant)
  const int L = blockIdx.x;
  const int xcd = L & 7, t = L >> 3;        // t in 0..127
  const int bh = xcd * 4 + (t >> 5);
  const int qj = 31 - ((t + bh * 7) & 31);  // heavy-first-ish, staggered
  const int b = bh >> 4, h = bh & 15;
  const ushort_t* base = kqv + (size_t)b * 2048 * 3072;
  const ushort_t* vbase = vt + (size_t)bh * 64 * 2048;

  // staging: 512 slots of 16B (K) + 512 (V); thread covers slot tid, tid+256.
  size_t kg[2], vg[2];
  int ld[2];
#pragma unroll
  for (int p = 0; p < 2; p++) {
    const int slot = tid + p * 256;
    const int srow = slot >> 3;
    const int scb = (((slot & 7) * 16) ^ ((srow & 7) << 4)) >> 1;  // elem off
    kg[p] = (size_t)srow * 3072 + h * 64 + scb;
    vg[p] = (size_t)srow * 2048 + scb;
    ld[p] = slot * 8;
  }

  // Q fragments (B-frag): rows wq0+q_rel, k = ds*16 + hi*8 + e
  const int wq0 = qj * 64 + qs * 32;
  bf16x8 qf[4];
#pragma unroll
  for (int ds = 0; ds < 4; ds++)
    qf[ds] = *(const bf16x8*)&base[(size_t)(wq0 + q_rel) * 3072 + 1024 + h * 64 +
                                   ds * 16 + hi * 8];

  f32x16 oacc[2] = {};
  const int nkt = qj + 1;  // causal K tiles for this 64-row q-tile

  // prologue: stage tile 0 into buffer 0
#pragma unroll
  for (int p = 0; p < 2; p++) {
    gload_lds16(&base[kg[p]], &lK[0][ld[p]]);
    gload_lds16(&vbase[vg[p]], &lVT[0][ld[p]]);
  }

  int cur = 0;
  for (int kt = 0; kt < nkt; ++kt) {
    // own tile-kt staging done; barrier makes all waves' staging visible
    asm volatile("s_waitcnt vmcnt(0)" ::: "memory");
    __builtin_amdgcn_s_barrier();
    asm volatile("" ::: "memory");

    // prefetch kt+1 into other buffer (safe: last read at kt-1, closed by
    // the barrier above); lands during compute of tile kt
    if (kt + 1 < nkt) {
#pragma unroll
      for (int p = 0; p < 2; p++) {
        gload_lds16(&base[(size_t)(kt + 1) * 64 * 3072 + kg[p]], &lK[cur ^ 1][ld[p]]);
        gload_lds16(&vbase[(size_t)(kt + 1) * 64 + vg[p]], &lVT[cur ^ 1][ld[p]]);
      }
    }

    const int kv0 = kt * 64 + kb * 32;  // this wave's kv sub-block base
    if (kv0 <= wq0 + 31) {              // skip fully-masked sub-block
      // St = K·Q^T (32x32): lane holds St[k][q=q_rel], k=(r&3)+8*(r>>2)+4*hi
      f32x16 st = {};
      const int krow = kb * 32 + q_rel;
      const int ksw = krow & 7;
#pragma unroll
      for (int ds = 0; ds < 4; ds++) {
        bf16x8 kf = *(const bf16x8*)&lK[cur][krow * 64 + (((ds * 2 + hi) ^ ksw) * 8)];
        st = __builtin_amdgcn_mfma_f32_32x32x16_bf16(kf, qf[ds], st, 0, 0, 0);
      }
      // causal mask
      if (kv0 + 31 > wq0) {
#pragma unroll
        for (int r = 0; r < 16; r++) {
          const int kgl = kv0 + (r & 3) + 8 * (r >> 2) + 4 * hi;
          if (kgl > wq0 + q_rel) st[r] = 0.f;
        }
      }
      // T12: f32 -> packed bf16 + permlane32_swap -> PV A-frags
      unsigned int w0, w1, w2, w3, w4, w5, w6, w7;
      {
        float e0 = st[0], e1 = st[1], e2 = st[2], e3 = st[3];
        float e4 = st[4], e5 = st[5], e6 = st[6], e7 = st[7];
        float e8 = st[8], e9 = st[9], e10 = st[10], e11 = st[11];
        float e12 = st[12], e13 = st[13], e14 = st[14], e15 = st[15];
        asm("v_cvt_pk_bf16_f32 %0, %1, %2" : "=v"(w0) : "v"(e0), "v"(e1));
        asm("v_cvt_pk_bf16_f32 %0, %1, %2" : "=v"(w1) : "v"(e2), "v"(e3));
        asm("v_cvt_pk_bf16_f32 %0, %1, %2" : "=v"(w2) : "v"(e4), "v"(e5));
        asm("v_cvt_pk_bf16_f32 %0, %1, %2" : "=v"(w3) : "v"(e6), "v"(e7));
        asm("v_cvt_pk_bf16_f32 %0, %1, %2" : "=v"(w4) : "v"(e8), "v"(e9));
        asm("v_cvt_pk_bf16_f32 %0, %1, %2" : "=v"(w5) : "v"(e10), "v"(e11));
        asm("v_cvt_pk_bf16_f32 %0, %1, %2" : "=v"(w6) : "v"(e12), "v"(e13));
        asm("v_cvt_pk_bf16_f32 %0, %1, %2" : "=v"(w7) : "v"(e14), "v"(e15));
      }
      asm("v_permlane32_swap_b32 %0, %1" : "+v"(w0), "+v"(w2));
      asm("v_permlane32_swap_b32 %0, %1" : "+v"(w1), "+v"(w3));
      asm("v_permlane32_swap_b32 %0, %1" : "+v"(w4), "+v"(w6));
      asm("v_permlane32_swap_b32 %0, %1" : "+v"(w5), "+v"(w7));
      uint4v u0 = {w0, w1, w2, w3};  // P[q][k = kv0 + hi*8 + 0..7]
      uint4v u1 = {w4, w5, w6, w7};  // P[q][k = kv0 + 16 + hi*8 + 0..7]
      bf16x8 pa0 = __builtin_bit_cast(bf16x8, u0);
      bf16x8 pa1 = __builtin_bit_cast(bf16x8, u1);
      // O_partial += P·V over this wave's 32-k slice
#pragma unroll
      for (int dt = 0; dt < 2; dt++) {
        const int vrow = dt * 32 + q_rel;
        const int vsw = vrow & 7;
        bf16x8 vf0 = *(const bf16x8*)&lVT[cur][vrow * 64 + (((kb * 4 + hi) ^ vsw) * 8)];
        bf16x8 vf1 = *(const bf16x8*)&lVT[cur][vrow * 64 + (((kb * 4 + 2 + hi) ^ vsw) * 8)];
        oacc[dt] = __builtin_amdgcn_mfma_f32_32x32x16_bf16(pa0, vf0, oacc[dt], 0, 0, 0);
        oacc[dt] = __builtin_amdgcn_mfma_f32_32x32x16_bf16(pa1, vf1, oacc[dt], 0, 0, 0);
      }
    }

    cur ^= 1;
  }

  // epilogue: cross-wave (kb) reduce via LDS f32 scratch (reuses lK)
  __syncthreads();
  float* red = (float*)&lK[0][0];  // 16 KB = 4096 f32
  if (kb == 1) {
#pragma unroll
    for (int dt = 0; dt < 2; dt++)
#pragma unroll
      for (int r = 0; r < 16; r++)
        red[qs * 2048 + (dt * 16 + r) * 64 + lane] = oacc[dt][r];
  }
  __syncthreads();
  if (kb == 0) {
#pragma unroll
    for (int dt = 0; dt < 2; dt++)
#pragma unroll
      for (int r = 0; r < 16; r++) {
        const float v = oacc[dt][r] + red[qs * 2048 + (dt * 16 + r) * 64 + lane];
        const int q = (r & 3) + 8 * (r >> 2) + 4 * hi;
        const int row = wq0 + q;
        const int col = h * 64 + dt * 32 + q_rel;
        ao[(size_t)(b * 2048 + row) * 1024 + col] = f2bf(v);
      }
  }
}

// ---------- launch ----------

extern "C" void kernel_launch(void* const* d_in, const int* in_sizes, int n_in,
                              void* d_out, int out_size, void* d_ws, size_t ws_size,
                              hipStream_t stream) {
  const float* x  = (const float*)d_in[0];
  const float* W1 = (const float*)d_in[1];
  const float* b1 = (const float*)d_in[2];
  const float* W2 = (const float*)d_in[3];
  const float* b2 = (const float*)d_in[4];
  float* out = (float*)d_out;

  char* ws = (char*)d_ws;
  ushort_t* xb  = (ushort_t*)(ws);                 //  8 MB: x bf16 [4096][1024]
  ushort_t* w1t = (ushort_t*)(ws + 8388608);       //  6 MB: W1^T bf16 [3072][1024]
  ushort_t* w2t = (ushort_t*)(ws + 14680064);      //  2 MB: W2^T bf16 [1024][1024]
  ushort_t* kqv = (ushort_t*)(ws + 16777216);      // 24 MB: kqv bf16 [4096][3072]
  ushort_t* ao  = (ushort_t*)(ws + 41943040);      //  8 MB: attn out bf16 [4096][1024]
  ushort_t* vtb = (ushort_t*)(ws);                 //  8 MB: V^T (aliases xb; xb dead after gemm1)

  f32_to_bf16_vec<<<2048, 256, 0, stream>>>(x, xb);
  transpose_f32_bf16<<<dim3(96, 32), 256, 0, stream>>>(W1, w1t, 1024, 3072);
  transpose_f32_bf16<<<dim3(32, 32), 256, 0, stream>>>(W2, w2t, 1024, 1024);
  gemm_bt<true ><<<dim3(24, 32), 256, 0, stream>>>(xb, w1t, b1, kqv, 4096, 3072, 1024);
  transpose_v<<<dim3(32, 32), 256, 0, stream>>>(kqv, vtb);
  attn_kernel<<<dim3(1024), 256, 0, stream>>>(kqv, vtb, ao);
  gemm_bt<false><<<dim3(8, 32), 256, 0, stream>>>(ao, w2t, b2, out, 4096, 1024, 1024);
}

// Round 9
// 186.961 us; speedup vs baseline: 1.1219x; 1.0652x over previous
//
#include <hip/hip_runtime.h>
#include <hip/hip_bf16.h>

typedef __bf16 bf16x8 __attribute__((ext_vector_type(8)));
typedef float f32x4 __attribute__((ext_vector_type(4)));
typedef float f32x16 __attribute__((ext_vector_type(16)));
typedef unsigned short ushort_t;
typedef unsigned short ushort8 __attribute__((ext_vector_type(8)));
typedef unsigned int uint4v __attribute__((ext_vector_type(4)));

// ---------- helpers ----------

__device__ inline void gload_lds16(const void* g, void* l) {
  __builtin_amdgcn_global_load_lds(
      (const __attribute__((address_space(1))) void*)g,
      (__attribute__((address_space(3))) void*)l, 16, 0, 0);
}

// fp32 -> bf16 round-to-nearest-even (bit manipulation)
__device__ inline ushort_t f2bf(float f) {
  unsigned int u = __float_as_uint(f);
  unsigned int lsb = (u >> 16) & 1u;
  u += 0x7fffu + lsb;
  return (ushort_t)(u >> 16);
}

// ---------- fused prep: x->bf16, W1->W1^T bf16, W2->W2^T bf16 ----------

__device__ inline void transpose_tile_f32_bf16(
    const float* __restrict__ in, ushort_t* __restrict__ out,
    int R, int C, int cx, int ry, int tid) {
  __shared__ float tile[32][33];
  const int tx = tid & 31, ty = tid >> 5;  // 32 x 8
  const int c0 = cx * 32, r0 = ry * 32;
#pragma unroll
  for (int i = 0; i < 32; i += 8)
    tile[ty + i][tx] = in[(size_t)(r0 + ty + i) * C + c0 + tx];
  __syncthreads();
#pragma unroll
  for (int i = 0; i < 32; i += 8)
    out[(size_t)(c0 + ty + i) * R + r0 + tx] = f2bf(tile[tx][ty + i]);
}

// grid = 2048 (x cvt) + 3072 (W1^T) + 1024 (W2^T) = 6144 blocks
__global__ __launch_bounds__(256) void prep_kernel(
    const float* __restrict__ x, const float* __restrict__ W1,
    const float* __restrict__ W2, ushort_t* __restrict__ xb,
    ushort_t* __restrict__ w1t, ushort_t* __restrict__ w2t) {
  const int bid = blockIdx.x;
  const int tid = threadIdx.x;
  if (bid < 2048) {
    int i = (bid * 256 + tid) * 8;
    float4 a = *(const float4*)&x[i];
    float4 b = *(const float4*)&x[i + 4];
    ushort8 o;
    o[0] = f2bf(a.x); o[1] = f2bf(a.y); o[2] = f2bf(a.z); o[3] = f2bf(a.w);
    o[4] = f2bf(b.x); o[5] = f2bf(b.y); o[6] = f2bf(b.z); o[7] = f2bf(b.w);
    *(ushort8*)&xb[i] = o;
  } else if (bid < 2048 + 3072) {
    const int t = bid - 2048;
    transpose_tile_f32_bf16(W1, w1t, 1024, 3072, t % 96, t / 96, tid);
  } else {
    const int t = bid - 5120;
    transpose_tile_f32_bf16(W2, w2t, 1024, 1024, t % 32, t / 32, tid);
  }
}

// V-part of kqv [4096][3072] -> vt[bh][64 dh][2048 t]  (bf16 transpose)
__global__ __launch_bounds__(256) void transpose_v(
    const ushort_t* __restrict__ kqv, ushort_t* __restrict__ vt) {
  __shared__ ushort_t tile[64 * 64];  // 16B-slot XOR swizzle
  const int tt = blockIdx.x;  // t tile (0..31)
  const int bh = blockIdx.y;  // 0..31
  const int b = bh >> 4, h = bh & 15;
  const int tid = threadIdx.x;
#pragma unroll
  for (int p = 0; p < 2; p++) {
    const int tr = (tid >> 3) + p * 32;
    const int c8 = tid & 7;
    ushort8 v = *(const ushort8*)&kqv[(size_t)(b * 2048 + tt * 64 + tr) * 3072 +
                                      2048 + h * 64 + c8 * 8];
    *(ushort8*)&tile[tr * 64 + ((c8 ^ (tr & 7)) * 8)] = v;
  }
  __syncthreads();
  const int d = tid & 63;
#pragma unroll
  for (int p = 0; p < 2; p++) {
    const int t8 = (tid >> 6) + p * 4;  // 8-t chunk 0..7
    ushort8 o;
#pragma unroll
    for (int j = 0; j < 8; j++) {
      const int t = t8 * 8 + j;
      o[j] = tile[t * 64 + (((d >> 3) ^ (t & 7)) * 8) + (d & 7)];
    }
    *(ushort8*)&vt[(size_t)(bh * 64 + d) * 2048 + tt * 64 + t8 * 8] = o;
  }
}

// ---------- GEMM: C = A @ B (+bias), A[M][K] bf16, BT[N][K] bf16 ----------
// 128x128 tile, BK=32, 4 waves. v2: 3-buffer depth-2 counted-vmcnt pipeline
// (T4; vmcnt(4) in steady state, never 0) + BK=32 XOR chunk-swizzle
// (source chunk ^(row&3), read chunk lhi^(row&3)) -> 8-way conflicts -> 4-way.

template <bool OUT_BF16>
__global__ __launch_bounds__(256) void gemm_bt(
    const ushort_t* __restrict__ A, const ushort_t* __restrict__ BT,
    const float* __restrict__ bias, void* __restrict__ Cout,
    int M, int N, int K) {
  __shared__ ushort_t lA[3][128 * 32];  // 24 KB
  __shared__ ushort_t lB[3][128 * 32];  // 24 KB
  const int tid = threadIdx.x;
  const int lane = tid & 63;
  const int wave = tid >> 6;
  const int wr = wave >> 1, wc = wave & 1;
  const int l16 = lane & 15, lhi = lane >> 4;
  const int bx = blockIdx.x, by = blockIdx.y;

  // staging: slot tid -> row = tid>>2 (two halves), swizzled chunk
  const int srow = tid >> 2;
  const int schunk = (tid & 3) ^ (srow & 3);
  const ushort_t* gA = A + (size_t)(by * 128 + srow) * K + schunk * 8;
  const ushort_t* gB = BT + (size_t)(bx * 128 + srow) * K + schunk * 8;

#define GSTAGE(buf, k0)                                            \
  do {                                                             \
    gload_lds16(gA + (k0), &lA[buf][tid * 8]);                     \
    gload_lds16(gA + (k0) + (size_t)64 * K, &lA[buf][tid * 8 + 2048]); \
    gload_lds16(gB + (k0), &lB[buf][tid * 8]);                     \
    gload_lds16(gB + (k0) + (size_t)64 * K, &lB[buf][tid * 8 + 2048]); \
  } while (0)

  f32x4 acc[4][4] = {};
  const int NK = K >> 5;

  GSTAGE(0, 0);
  GSTAGE(1, 32);

  int cur = 0;
  for (int kt = 0; kt < NK; ++kt) {
    if (kt + 1 < NK) asm volatile("s_waitcnt vmcnt(4)" ::: "memory");
    else             asm volatile("s_waitcnt vmcnt(0)" ::: "memory");
    __builtin_amdgcn_s_barrier();
    asm volatile("" ::: "memory");

    if (kt + 2 < NK) {
      const int pf = (cur + 2 >= 3) ? cur - 1 : cur + 2;
      GSTAGE(pf, (kt + 2) * 32);
    }

    bf16x8 af[4], bfr[4];
#pragma unroll
    for (int m = 0; m < 4; m++) {
      const int row = wr * 64 + m * 16 + l16;
      af[m] = *(const bf16x8*)&lA[cur][row * 32 + ((lhi ^ (row & 3)) * 8)];
    }
#pragma unroll
    for (int n = 0; n < 4; n++) {
      const int row = wc * 64 + n * 16 + l16;
      bfr[n] = *(const bf16x8*)&lB[cur][row * 32 + ((lhi ^ (row & 3)) * 8)];
    }
#pragma unroll
    for (int m = 0; m < 4; m++)
#pragma unroll
      for (int n = 0; n < 4; n++)
        acc[m][n] = __builtin_amdgcn_mfma_f32_16x16x32_bf16(af[m], bfr[n],
                                                            acc[m][n], 0, 0, 0);
    cur = (cur + 1 >= 3) ? 0 : cur + 1;
  }
#undef GSTAGE

  const int r0 = by * 128 + wr * 64 + lhi * 4;
  const int c0 = bx * 128 + wc * 64 + l16;
#pragma unroll
  for (int m = 0; m < 4; m++)
#pragma unroll
    for (int n = 0; n < 4; n++) {
      const int col = c0 + n * 16;
      const float bv = bias[col];
#pragma unroll
      for (int j = 0; j < 4; j++) {
        const int row = r0 + m * 16 + j;
        const float v = acc[m][n][j] + bv;
        if (OUT_BF16)
          ((ushort_t*)Cout)[(size_t)row * N + col] = f2bf(v);
        else
          ((float*)Cout)[(size_t)row * N + col] = v;
      }
    }
}

// ---------- attention (softmax-free, causal) ----------
// (unchanged — round-7-verified control)

__global__ __launch_bounds__(256) void attn_kernel(
    const ushort_t* __restrict__ kqv, const ushort_t* __restrict__ vt,
    ushort_t* __restrict__ ao) {
  __shared__ ushort_t lK[2][64 * 64];   // 16 KB
  __shared__ ushort_t lVT[2][64 * 64];  // 16 KB
  const int tid = threadIdx.x, lane = tid & 63, wave = tid >> 6;
  const int q_rel = lane & 31, hi = lane >> 5;
  const int qs = wave & 1, kb = wave >> 1;
  const int L = blockIdx.x;
  const int xcd = L & 7, t = L >> 3;        // t in 0..127
  const int bh = xcd * 4 + (t >> 5);
  const int qj = 31 - ((t + bh * 7) & 31);  // heavy-first-ish, staggered
  const int b = bh >> 4, h = bh & 15;
  const ushort_t* base = kqv + (size_t)b * 2048 * 3072;
  const ushort_t* vbase = vt + (size_t)bh * 64 * 2048;

  size_t kg[2], vg[2];
  int ld[2];
#pragma unroll
  for (int p = 0; p < 2; p++) {
    const int slot = tid + p * 256;
    const int srow = slot >> 3;
    const int scb = (((slot & 7) * 16) ^ ((srow & 7) << 4)) >> 1;  // elem off
    kg[p] = (size_t)srow * 3072 + h * 64 + scb;
    vg[p] = (size_t)srow * 2048 + scb;
    ld[p] = slot * 8;
  }

  const int wq0 = qj * 64 + qs * 32;
  bf16x8 qf[4];
#pragma unroll
  for (int ds = 0; ds < 4; ds++)
    qf[ds] = *(const bf16x8*)&base[(size_t)(wq0 + q_rel) * 3072 + 1024 + h * 64 +
                                   ds * 16 + hi * 8];

  f32x16 oacc[2] = {};
  const int nkt = qj + 1;

#pragma unroll
  for (int p = 0; p < 2; p++) {
    gload_lds16(&base[kg[p]], &lK[0][ld[p]]);
    gload_lds16(&vbase[vg[p]], &lVT[0][ld[p]]);
  }

  int cur = 0;
  for (int kt = 0; kt < nkt; ++kt) {
    asm volatile("s_waitcnt vmcnt(0)" ::: "memory");
    __builtin_amdgcn_s_barrier();
    asm volatile("" ::: "memory");

    if (kt + 1 < nkt) {
#pragma unroll
      for (int p = 0; p < 2; p++) {
        gload_lds16(&base[(size_t)(kt + 1) * 64 * 3072 + kg[p]], &lK[cur ^ 1][ld[p]]);
        gload_lds16(&vbase[(size_t)(kt + 1) * 64 + vg[p]], &lVT[cur ^ 1][ld[p]]);
      }
    }

    const int kv0 = kt * 64 + kb * 32;
    if (kv0 <= wq0 + 31) {
      f32x16 st = {};
      const int krow = kb * 32 + q_rel;
      const int ksw = krow & 7;
#pragma unroll
      for (int ds = 0; ds < 4; ds++) {
        bf16x8 kf = *(const bf16x8*)&lK[cur][krow * 64 + (((ds * 2 + hi) ^ ksw) * 8)];
        st = __builtin_amdgcn_mfma_f32_32x32x16_bf16(kf, qf[ds], st, 0, 0, 0);
      }
      if (kv0 + 31 > wq0) {
#pragma unroll
        for (int r = 0; r < 16; r++) {
          const int kgl = kv0 + (r & 3) + 8 * (r >> 2) + 4 * hi;
          if (kgl > wq0 + q_rel) st[r] = 0.f;
        }
      }
      unsigned int w0, w1, w2, w3, w4, w5, w6, w7;
      {
        float e0 = st[0], e1 = st[1], e2 = st[2], e3 = st[3];
        float e4 = st[4], e5 = st[5], e6 = st[6], e7 = st[7];
        float e8 = st[8], e9 = st[9], e10 = st[10], e11 = st[11];
        float e12 = st[12], e13 = st[13], e14 = st[14], e15 = st[15];
        asm("v_cvt_pk_bf16_f32 %0, %1, %2" : "=v"(w0) : "v"(e0), "v"(e1));
        asm("v_cvt_pk_bf16_f32 %0, %1, %2" : "=v"(w1) : "v"(e2), "v"(e3));
        asm("v_cvt_pk_bf16_f32 %0, %1, %2" : "=v"(w2) : "v"(e4), "v"(e5));
        asm("v_cvt_pk_bf16_f32 %0, %1, %2" : "=v"(w3) : "v"(e6), "v"(e7));
        asm("v_cvt_pk_bf16_f32 %0, %1, %2" : "=v"(w4) : "v"(e8), "v"(e9));
        asm("v_cvt_pk_bf16_f32 %0, %1, %2" : "=v"(w5) : "v"(e10), "v"(e11));
        asm("v_cvt_pk_bf16_f32 %0, %1, %2" : "=v"(w6) : "v"(e12), "v"(e13));
        asm("v_cvt_pk_bf16_f32 %0, %1, %2" : "=v"(w7) : "v"(e14), "v"(e15));
      }
      asm("v_permlane32_swap_b32 %0, %1" : "+v"(w0), "+v"(w2));
      asm("v_permlane32_swap_b32 %0, %1" : "+v"(w1), "+v"(w3));
      asm("v_permlane32_swap_b32 %0, %1" : "+v"(w4), "+v"(w6));
      asm("v_permlane32_swap_b32 %0, %1" : "+v"(w5), "+v"(w7));
      uint4v u0 = {w0, w1, w2, w3};
      uint4v u1 = {w4, w5, w6, w7};
      bf16x8 pa0 = __builtin_bit_cast(bf16x8, u0);
      bf16x8 pa1 = __builtin_bit_cast(bf16x8, u1);
#pragma unroll
      for (int dt = 0; dt < 2; dt++) {
        const int vrow = dt * 32 + q_rel;
        const int vsw = vrow & 7;
        bf16x8 vf0 = *(const bf16x8*)&lVT[cur][vrow * 64 + (((kb * 4 + hi) ^ vsw) * 8)];
        bf16x8 vf1 = *(const bf16x8*)&lVT[cur][vrow * 64 + (((kb * 4 + 2 + hi) ^ vsw) * 8)];
        oacc[dt] = __builtin_amdgcn_mfma_f32_32x32x16_bf16(pa0, vf0, oacc[dt], 0, 0, 0);
        oacc[dt] = __builtin_amdgcn_mfma_f32_32x32x16_bf16(pa1, vf1, oacc[dt], 0, 0, 0);
      }
    }

    cur ^= 1;
  }

  __syncthreads();
  float* red = (float*)&lK[0][0];
  if (kb == 1) {
#pragma unroll
    for (int dt = 0; dt < 2; dt++)
#pragma unroll
      for (int r = 0; r < 16; r++)
        red[qs * 2048 + (dt * 16 + r) * 64 + lane] = oacc[dt][r];
  }
  __syncthreads();
  if (kb == 0) {
#pragma unroll
    for (int dt = 0; dt < 2; dt++)
#pragma unroll
      for (int r = 0; r < 16; r++) {
        const float v = oacc[dt][r] + red[qs * 2048 + (dt * 16 + r) * 64 + lane];
        const int q = (r & 3) + 8 * (r >> 2) + 4 * hi;
        const int row = wq0 + q;
        const int col = h * 64 + dt * 32 + q_rel;
        ao[(size_t)(b * 2048 + row) * 1024 + col] = f2bf(v);
      }
  }
}

// ---------- launch ----------

extern "C" void kernel_launch(void* const* d_in, const int* in_sizes, int n_in,
                              void* d_out, int out_size, void* d_ws, size_t ws_size,
                              hipStream_t stream) {
  const float* x  = (const float*)d_in[0];
  const float* W1 = (const float*)d_in[1];
  const float* b1 = (const float*)d_in[2];
  const float* W2 = (const float*)d_in[3];
  const float* b2 = (const float*)d_in[4];
  float* out = (float*)d_out;

  char* ws = (char*)d_ws;
  ushort_t* xb  = (ushort_t*)(ws);                 //  8 MB: x bf16 [4096][1024]
  ushort_t* w1t = (ushort_t*)(ws + 8388608);       //  6 MB: W1^T bf16 [3072][1024]
  ushort_t* w2t = (ushort_t*)(ws + 14680064);      //  2 MB: W2^T bf16 [1024][1024]
  ushort_t* kqv = (ushort_t*)(ws + 16777216);      // 24 MB: kqv bf16 [4096][3072]
  ushort_t* ao  = (ushort_t*)(ws + 41943040);      //  8 MB: attn out bf16 [4096][1024]
  ushort_t* vtb = (ushort_t*)(ws);                 //  8 MB: V^T (aliases xb; xb dead after gemm1)

  prep_kernel<<<6144, 256, 0, stream>>>(x, W1, W2, xb, w1t, w2t);
  gemm_bt<true ><<<dim3(24, 32), 256, 0, stream>>>(xb, w1t, b1, kqv, 4096, 3072, 1024);
  transpose_v<<<dim3(32, 32), 256, 0, stream>>>(kqv, vtb);
  attn_kernel<<<dim3(1024), 256, 0, stream>>>(kqv, vtb, ao);
  gemm_bt<false><<<dim3(8, 32), 256, 0, stream>>>(ao, w2t, b2, out, 4096, 1024, 1024);
}